// Round 7
// baseline (38.582 us; speedup 1.0000x reference)
//
#include <hip/hip_runtime.h>
#include <math.h>

#define N1V    8192
#define N2V    8192
#define BLOCK  512                // 8 waves
#define NW     8
#define NOCT   16                 // N1 split into 16 chunks across blockIdx.y
#define OCT    (N1V / NOCT)       // 512 points staged per block
#define TILES  (OCT / 16)         // 32 MFMA tiles per scan
#define QPW    16                 // queries per wave (MFMA N dim)
#define QPB    (NW * QPW)         // 128 queries per block
#define TKEYMASK 0xFFFFFFE0u      // tile key: low 5 bits = tile id
#define TMASK    0x1Fu
#define PKEYMASK 0xFFFFFC00u      // point key: low 10 bits = local point idx
#define PMASK    0x3FFu
#define FMAXV  __uint_as_float(0x7F7FFFFFu)

typedef __attribute__((ext_vector_type(8))) short short8;
typedef __attribute__((ext_vector_type(4))) float float4v;

// split f32 into bf16 hi (truncate) + bf16 lo (truncate of remainder)
__device__ __forceinline__ void bsplit(float x, unsigned short& h, unsigned short& l) {
    unsigned hb = __float_as_uint(x) & 0xFFFF0000u;
    h = (unsigned short)(hb >> 16);
    float lo = x - __uint_as_float(hb);
    l = (unsigned short)(__float_as_uint(lo) >> 16);
}

// K-slot schedule (A = point rows, B = query cols), d' = |s|^2 - 2 q.s :
//  k0-2: s_h * -2q_h   k3-5: s_l * -2q_h   k6-8: s_h * -2q_l
//  k9: w_h * 1   k10: w_l * 1   k11-31: B zero -> A content irrelevant
__global__ __launch_bounds__(BLOCK, 8)
void knn_part(const float* __restrict__ xyz1,
              const float* __restrict__ xyz2,
              const float* __restrict__ flow1,
              float2* __restrict__ ws)
{
    __shared__ __align__(16) unsigned short sA[TILES * 256]; // 16 KB bf16 A-frags
    __shared__ float4 sPts[OCT];                             // 8 KB exact points
    __shared__ float  sCand[NW][64 * 3];                     // 6 KB packed top-3

    const int b     = blockIdx.z;
    const int oc    = blockIdx.y;
    const int qbase = blockIdx.x * QPB;
    const int t     = threadIdx.x;
    const int lane  = t & 63;
    const int w     = t >> 6;

    const float* x1 = xyz1 + b * 3 * N1V + oc * OCT;
    const float* f1 = flow1 + b * 3 * N1V + oc * OCT;
    const float* x2 = xyz2 + b * 3 * N2V;

    // ---- stage: exact f32 points + pre-split bf16 A-fragments (1 pt/thread)
    {
        const int j = t;
        float sx = x1[j]           + f1[j];
        float sy = x1[N1V + j]     + f1[N1V + j];
        float sz = x1[2*N1V + j]   + f1[2*N1V + j];
        float wv = fmaf(sx, sx, fmaf(sy, sy, sz * sz));
        sPts[j] = make_float4(sx, sy, sz, wv);
        unsigned short xh,xl,yh,yl,zh,zl,wh,wl;
        bsplit(sx, xh, xl); bsplit(sy, yh, yl);
        bsplit(sz, zh, zl); bsplit(wv, wh, wl);
        unsigned base = (unsigned)(j >> 4) * 256u + (unsigned)(j & 15) * 8u;
        *(uint4*)&sA[base] = make_uint4(
            (unsigned)xh | ((unsigned)yh << 16),
            (unsigned)zh | ((unsigned)xl << 16),
            (unsigned)yl | ((unsigned)zl << 16),
            (unsigned)xh | ((unsigned)yh << 16));
        *(uint4*)&sA[base + 128] = make_uint4(
            (unsigned)zh | ((unsigned)wh << 16),
            (unsigned)wl, 0u, 0u);
    }

    // ---- B fragment: this wave's 16 queries ---------------------------------
    const int col = lane & 15;
    const int g   = lane >> 4;
    const int qi  = qbase + w * QPW + col;
    const float qx = x2[qi], qy = x2[N2V + qi], qz = x2[2*N2V + qi];

    unsigned short qxh,qxl,qyh,qyl,qzh,qzl;
    bsplit(-2.0f * qx, qxh, qxl);
    bsplit(-2.0f * qy, qyh, qyl);
    bsplit(-2.0f * qz, qzh, qzl);
    short8 bf = {0,0,0,0,0,0,0,0};
    if (g == 0) {
        bf[0]=(short)qxh; bf[1]=(short)qyh; bf[2]=(short)qzh;
        bf[3]=(short)qxh; bf[4]=(short)qyh; bf[5]=(short)qzh;
        bf[6]=(short)qxl; bf[7]=(short)qyl;
    } else if (g == 1) {
        bf[0]=(short)qzl; bf[1]=(short)0x3F80; bf[2]=(short)0x3F80;  // 1.0 bf16
    }

    // all lanes read real A data; lanes with k>=16 multiply zero B slots
    const unsigned short* ap = &sA[(unsigned)(((g & 1) * 128) + col * 8)];

    __syncthreads();

    // ---- MFMA scan, tournament selection: ~6 VALU per 4 pairs ---------------
    float c0 = FMAXV, c1 = FMAXV, c2 = FMAXV;
    const float4v zc = {0.0f, 0.0f, 0.0f, 0.0f};
    #pragma unroll
    for (int tl = 0; tl < TILES; ++tl) {
        short8 a = *(const short8*)(ap + tl * 256);     // offset-imm ds_read_b128
        float4v acc = __builtin_amdgcn_mfma_f32_16x16x32_bf16(a, bf, zc, 0, 0, 0);
        float m = fminf(fminf(fminf(acc[0], acc[1]), acc[2]), acc[3]); // min3+min
        float kf = __uint_as_float((__float_as_uint(m) & TKEYMASK) | (unsigned)tl);
        c2 = __builtin_amdgcn_fmed3f(c1, c2, kf);
        c1 = __builtin_amdgcn_fmed3f(c0, c1, kf);
        c0 = fminf(c0, kf);
    }

    // ---- refine: expand 3 winning tiles (4 pts each) with exact f32 d2 ------
    float e0 = FMAXV, e1 = FMAXV, e2 = FMAXV;
    const int g4 = g * 4;
    #pragma unroll
    for (int m = 0; m < 3; ++m) {
        float km = (m == 0) ? c0 : (m == 1) ? c1 : c2;
        int base = ((int)(__float_as_uint(km) & TMASK)) * 16 + g4;
        #pragma unroll
        for (int p = 0; p < 4; ++p) {
            float4 P = sPts[base + p];
            float dx = P.x - qx, dy = P.y - qy, dz = P.z - qz;
            float d  = fmaf(dx, dx, fmaf(dy, dy, dz * dz));
            float pk = __uint_as_float((__float_as_uint(d) & PKEYMASK)
                                       | (unsigned)(base + p));
            e2 = __builtin_amdgcn_fmed3f(e1, e2, pk);
            e1 = __builtin_amdgcn_fmed3f(e0, e1, pk);
            e0 = fminf(e0, pk);
        }
    }

    // ---- within-wave exchange of the 4 lane-groups' triples -----------------
    sCand[w][lane*3 + 0] = e0;
    sCand[w][lane*3 + 1] = e1;
    sCand[w][lane*3 + 2] = e2;

    if (lane < 16) {
        float b0 = FMAXV, b1 = FMAXV, b2 = FMAXV;
        #pragma unroll
        for (int gg = 0; gg < 4; ++gg) {
            #pragma unroll
            for (int m = 0; m < 3; ++m) {
                float pk = sCand[w][(gg*16 + lane)*3 + m];
                b2 = __builtin_amdgcn_fmed3f(b1, b2, pk);
                b1 = __builtin_amdgcn_fmed3f(b0, b1, pk);
                b0 = fminf(b0, pk);
            }
        }
        float2* wq = ws + ((size_t)(b * NOCT + oc) * N2V + qi) * 3;
        wq[0] = make_float2(__uint_as_float(__float_as_uint(b0) & PKEYMASK),
                            __int_as_float(oc * OCT + (int)(__float_as_uint(b0) & PMASK)));
        wq[1] = make_float2(__uint_as_float(__float_as_uint(b1) & PKEYMASK),
                            __int_as_float(oc * OCT + (int)(__float_as_uint(b1) & PMASK)));
        wq[2] = make_float2(__uint_as_float(__float_as_uint(b2) & PKEYMASK),
                            __int_as_float(oc * OCT + (int)(__float_as_uint(b2) & PMASK)));
    }
}

// ---- pass 2: merge 16 chunks, weights, flow gather, output -----------------
__global__ __launch_bounds__(64)
void knn_merge(const float* __restrict__ xyz2,
               const float* __restrict__ flow1,
               const float2* __restrict__ ws,
               float* __restrict__ out)
{
    const int gid = blockIdx.x * 64 + threadIdx.x;
    const int b   = gid / N2V;
    const int qi  = gid - b * N2V;

    float b0 = FMAXV, b1 = FMAXV, b2 = FMAXV;
    int   j0 = 0, j1 = 0, j2 = 0;
    for (int oc = 0; oc < NOCT; ++oc) {
        const float2* wq = ws + ((size_t)(b * NOCT + oc) * N2V + qi) * 3;
        #pragma unroll
        for (int m = 0; m < 3; ++m) {
            float2 c = wq[m];
            float d = c.x;
            int   j = __float_as_int(c.y);
            if (d < b2) {
                if (d < b1) {
                    b2 = b1; j2 = j1;
                    if (d < b0) { b1 = b0; j1 = j0; b0 = d; j0 = j; }
                    else        { b1 = d;  j1 = j; }
                } else { b2 = d; j2 = j; }
            }
        }
    }

    float d0 = fmaxf(sqrtf(fmaxf(b0, 0.0f)), 1e-10f);
    float d1 = fmaxf(sqrtf(fmaxf(b1, 0.0f)), 1e-10f);
    float d2 = fmaxf(sqrtf(fmaxf(b2, 0.0f)), 1e-10f);
    float i0 = 1.0f / d0, i1 = 1.0f / d1, i2 = 1.0f / d2;
    float wsum = i0 + i1 + i2;
    float w0 = i0 / wsum, w1 = i1 / wsum, w2 = i2 / wsum;

    const float* f1 = flow1 + b * 3 * N1V;
    const float* x2 = xyz2 + b * 3 * N2V;
    float fxo = w0 * f1[j0]         + w1 * f1[j1]         + w2 * f1[j2];
    float fyo = w0 * f1[N1V + j0]   + w1 * f1[N1V + j1]   + w2 * f1[N1V + j2];
    float fzo = w0 * f1[2*N1V + j0] + w1 * f1[2*N1V + j1] + w2 * f1[2*N1V + j2];

    float* ob = out + b * 3 * N2V;
    ob[qi]         = x2[qi]         - fxo;
    ob[N2V + qi]   = x2[N2V + qi]   - fyo;
    ob[2*N2V + qi] = x2[2*N2V + qi] - fzo;
}

extern "C" void kernel_launch(void* const* d_in, const int* in_sizes, int n_in,
                              void* d_out, int out_size, void* d_ws, size_t ws_size,
                              hipStream_t stream)
{
    const float* xyz1  = (const float*)d_in[0];
    const float* xyz2  = (const float*)d_in[1];
    const float* flow1 = (const float*)d_in[2];
    float* out = (float*)d_out;
    const int B = in_sizes[0] / (3 * N1V);

    float2* ws = (float2*)d_ws;   // B * NOCT * N2V * 3 * 8 B = 6.3 MB @ B=2

    dim3 grid(N2V / QPB, NOCT, B);    // (64, 16, B) = 2048 blocks, 4 blocks/CU
    knn_part<<<grid, BLOCK, 0, stream>>>(xyz1, xyz2, flow1, ws);

    knn_merge<<<(B * N2V) / 64, 64, 0, stream>>>(xyz2, flow1, ws, out);
}

// Round 8
// 34.438 us; speedup vs baseline: 1.1203x; 1.1203x over previous
//
#include <hip/hip_runtime.h>
#include <math.h>

#define N1V    8192
#define N2V    8192
#define BLOCK  1024               // 16 waves
#define NW     16
#define NOCT   16                 // N1 split into 16 chunks across blockIdx.y
#define OCT    (N1V / NOCT)       // 512 points staged per block
#define TILES  (OCT / 16)         // 32 MFMA tiles per scan
#define QPW    64                 // queries per wave = 4 MFMA column-sets
#define QPB    (NW * QPW)         // 1024 queries per block
#define SKEYMASK 0xFFFFFF80u      // stripe key: 16 mantissa bits, low 7 = stripe id
#define SMASK    0x7Fu
#define PKEYMASK 0xFFFFFE00u      // point key: 14 mantissa bits, low 9 = local idx
#define PMASK    0x1FFu
#define FMAXV  __uint_as_float(0x7F7FFFFFu)

typedef __attribute__((ext_vector_type(8))) short short8;
typedef __attribute__((ext_vector_type(4))) float float4v;

// sorted top-3 insert: t0 <= t1 <= t2
#define INS3(t0,t1,t2,v) do { \
    t2 = __builtin_amdgcn_fmed3f(t1, t2, v); \
    t1 = __builtin_amdgcn_fmed3f(t0, t1, v); \
    t0 = fminf(t0, v); } while (0)

// split f32 into bf16 hi (truncate) + bf16 lo (truncate of remainder)
__device__ __forceinline__ void bsplit(float x, unsigned short& h, unsigned short& l) {
    unsigned hb = __float_as_uint(x) & 0xFFFF0000u;
    h = (unsigned short)(hb >> 16);
    float lo = x - __uint_as_float(hb);
    l = (unsigned short)(__float_as_uint(lo) >> 16);
}

// K-slot schedule (A = point rows, B = query cols), d' = |s|^2 - 2 q.s :
//  k0-2: s_h * -2q_h   k3-5: s_l * -2q_h   k6-8: s_h * -2q_l
//  k9: w_h * 1   k10: w_l * 1   k11-31: B zero -> A content irrelevant
__global__ __launch_bounds__(BLOCK, 4)
void knn_part(const float* __restrict__ xyz1,
              const float* __restrict__ xyz2,
              const float* __restrict__ flow1,
              float2* __restrict__ ws)
{
    __shared__ __align__(16) unsigned short sA[TILES * 256]; // 16 KB bf16 A-frags
    __shared__ float4 sPts[OCT];                             // 8 KB exact points

    const int b     = blockIdx.z;
    const int oc    = blockIdx.y;
    const int qbase = blockIdx.x * QPB;
    const int t     = threadIdx.x;
    const int lane  = t & 63;
    const int w     = t >> 6;
    const int col   = lane & 15;
    const int g     = lane >> 4;

    const float* x1 = xyz1 + b * 3 * N1V + oc * OCT;
    const float* f1 = flow1 + b * 3 * N1V + oc * OCT;
    const float* x2 = xyz2 + b * 3 * N2V;

    // ---- stage: exact f32 points + pre-split bf16 A-fragments -------------
    if (t < OCT) {
        const int j = t;
        float sx = x1[j]           + f1[j];
        float sy = x1[N1V + j]     + f1[N1V + j];
        float sz = x1[2*N1V + j]   + f1[2*N1V + j];
        float wv = fmaf(sx, sx, fmaf(sy, sy, sz * sz));
        sPts[j] = make_float4(sx, sy, sz, wv);
        unsigned short xh,xl,yh,yl,zh,zl,wh,wl;
        bsplit(sx, xh, xl); bsplit(sy, yh, yl);
        bsplit(sz, zh, zl); bsplit(wv, wh, wl);
        unsigned base = (unsigned)(j >> 4) * 256u + (unsigned)(j & 15) * 8u;
        *(uint4*)&sA[base] = make_uint4(
            (unsigned)xh | ((unsigned)yh << 16),
            (unsigned)zh | ((unsigned)xl << 16),
            (unsigned)yl | ((unsigned)zl << 16),
            (unsigned)xh | ((unsigned)yh << 16));
        *(uint4*)&sA[base + 128] = make_uint4(
            (unsigned)zh | ((unsigned)wh << 16),
            (unsigned)wl, 0u, 0u);
    }

    // ---- B fragments: 4 query column-sets per wave ------------------------
    float qxr = 0.f, qyr = 0.f, qzr = 0.f;   // exact query for refine (qset g)
    short8 bfr[4];
    #pragma unroll
    for (int k = 0; k < 4; ++k) {
        int qi = qbase + w * QPW + k * 16 + col;
        float qx = x2[qi], qy = x2[N2V + qi], qz = x2[2*N2V + qi];
        if (k == g) { qxr = qx; qyr = qy; qzr = qz; }
        unsigned short xh,xl,yh,yl,zh,zl;
        bsplit(-2.0f * qx, xh, xl);
        bsplit(-2.0f * qy, yh, yl);
        bsplit(-2.0f * qz, zh, zl);
        short8 bf = {0,0,0,0,0,0,0,0};
        if (g == 0) {
            bf[0]=(short)xh; bf[1]=(short)yh; bf[2]=(short)zh;
            bf[3]=(short)xh; bf[4]=(short)yh; bf[5]=(short)zh;
            bf[6]=(short)xl; bf[7]=(short)yl;
        } else if (g == 1) {
            bf[0]=(short)zl; bf[1]=(short)0x3F80; bf[2]=(short)0x3F80;  // 1.0
        }
        bfr[k] = bf;
    }

    const unsigned short* ap = &sA[(unsigned)(((g & 1) * 128) + col * 8)];

    __syncthreads();

    // ---- MFMA scan: 1 ds_read feeds 4 MFMAs; stripe tournament ------------
    float c[4][3];
    #pragma unroll
    for (int k = 0; k < 4; ++k) { c[k][0] = FMAXV; c[k][1] = FMAXV; c[k][2] = FMAXV; }

    const float4v zc = {0.0f, 0.0f, 0.0f, 0.0f};
    #pragma unroll
    for (int tl = 0; tl < TILES; ++tl) {
        short8 a = *(const short8*)(ap + tl * 256);   // offset-imm ds_read_b128
        unsigned sid = (unsigned)(tl << 2) | (unsigned)g;
        #pragma unroll
        for (int k = 0; k < 4; ++k) {
            float4v acc = __builtin_amdgcn_mfma_f32_16x16x32_bf16(a, bfr[k], zc, 0, 0, 0);
            float m = fminf(fminf(fminf(acc[0], acc[1]), acc[2]), acc[3]);
            float kf = __uint_as_float((__float_as_uint(m) & SKEYMASK) | sid);
            INS3(c[k][0], c[k][1], c[k][2], kf);
        }
    }

    // ---- butterfly merge of stripe keys across the 4 lane groups ----------
    #pragma unroll
    for (int k = 0; k < 4; ++k) {
        #pragma unroll
        for (int d = 16; d <= 32; d <<= 1) {
            float r0 = __shfl_xor(c[k][0], d, 64);
            float r1 = __shfl_xor(c[k][1], d, 64);
            float r2 = __shfl_xor(c[k][2], d, 64);
            INS3(c[k][0], c[k][1], c[k][2], r0);
            INS3(c[k][0], c[k][1], c[k][2], r1);
            INS3(c[k][0], c[k][1], c[k][2], r2);
        }
    }

    // ---- group g refines qset g: 3 stripes x 4 points, exact f32 d2 -------
    float s0 = (g==0) ? c[0][0] : (g==1) ? c[1][0] : (g==2) ? c[2][0] : c[3][0];
    float s1 = (g==0) ? c[0][1] : (g==1) ? c[1][1] : (g==2) ? c[2][1] : c[3][1];
    float s2 = (g==0) ? c[0][2] : (g==1) ? c[1][2] : (g==2) ? c[2][2] : c[3][2];

    float e0 = FMAXV, e1 = FMAXV, e2 = FMAXV;
    #pragma unroll
    for (int m = 0; m < 3; ++m) {
        float km = (m == 0) ? s0 : (m == 1) ? s1 : s2;
        unsigned sid = __float_as_uint(km) & SMASK;
        int pb = (int)((sid >> 2) * 16 + (sid & 3) * 4);
        #pragma unroll
        for (int p = 0; p < 4; ++p) {
            float4 P = sPts[pb + p];
            float dx = P.x - qxr, dy = P.y - qyr, dz = P.z - qzr;
            float d  = fmaf(dx, dx, fmaf(dy, dy, dz * dz));
            float pk = __uint_as_float((__float_as_uint(d) & PKEYMASK)
                                       | (unsigned)(pb + p));
            INS3(e0, e1, e2, pk);
        }
    }

    // ---- every lane writes its own query's triple (coalesced, 24B/lane) ---
    {
        const int qir = qbase + w * QPW + lane;   // g*16+col == lane
        float2* wq = ws + ((size_t)(b * NOCT + oc) * N2V + qir) * 3;
        wq[0] = make_float2(__uint_as_float(__float_as_uint(e0) & PKEYMASK),
                            __int_as_float(oc * OCT + (int)(__float_as_uint(e0) & PMASK)));
        wq[1] = make_float2(__uint_as_float(__float_as_uint(e1) & PKEYMASK),
                            __int_as_float(oc * OCT + (int)(__float_as_uint(e1) & PMASK)));
        wq[2] = make_float2(__uint_as_float(__float_as_uint(e2) & PKEYMASK),
                            __int_as_float(oc * OCT + (int)(__float_as_uint(e2) & PMASK)));
    }
}

// ---- pass 2: merge 16 chunks, weights, flow gather, output -----------------
__global__ __launch_bounds__(64)
void knn_merge(const float* __restrict__ xyz2,
               const float* __restrict__ flow1,
               const float2* __restrict__ ws,
               float* __restrict__ out)
{
    const int gid = blockIdx.x * 64 + threadIdx.x;
    const int b   = gid / N2V;
    const int qi  = gid - b * N2V;

    float b0 = FMAXV, b1 = FMAXV, b2 = FMAXV;
    int   j0 = 0, j1 = 0, j2 = 0;
    for (int oc = 0; oc < NOCT; ++oc) {
        const float2* wq = ws + ((size_t)(b * NOCT + oc) * N2V + qi) * 3;
        #pragma unroll
        for (int m = 0; m < 3; ++m) {
            float2 c = wq[m];
            float d = c.x;
            int   j = __float_as_int(c.y);
            if (d < b2) {
                if (d < b1) {
                    b2 = b1; j2 = j1;
                    if (d < b0) { b1 = b0; j1 = j0; b0 = d; j0 = j; }
                    else        { b1 = d;  j1 = j; }
                } else { b2 = d; j2 = j; }
            }
        }
    }

    float d0 = fmaxf(sqrtf(fmaxf(b0, 0.0f)), 1e-10f);
    float d1 = fmaxf(sqrtf(fmaxf(b1, 0.0f)), 1e-10f);
    float d2 = fmaxf(sqrtf(fmaxf(b2, 0.0f)), 1e-10f);
    float i0 = 1.0f / d0, i1 = 1.0f / d1, i2 = 1.0f / d2;
    float wsum = i0 + i1 + i2;
    float w0 = i0 / wsum, w1 = i1 / wsum, w2 = i2 / wsum;

    const float* f1 = flow1 + b * 3 * N1V;
    const float* x2 = xyz2 + b * 3 * N2V;
    float fxo = w0 * f1[j0]         + w1 * f1[j1]         + w2 * f1[j2];
    float fyo = w0 * f1[N1V + j0]   + w1 * f1[N1V + j1]   + w2 * f1[N1V + j2];
    float fzo = w0 * f1[2*N1V + j0] + w1 * f1[2*N1V + j1] + w2 * f1[2*N1V + j2];

    float* ob = out + b * 3 * N2V;
    ob[qi]         = x2[qi]         - fxo;
    ob[N2V + qi]   = x2[N2V + qi]   - fyo;
    ob[2*N2V + qi] = x2[2*N2V + qi] - fzo;
}

extern "C" void kernel_launch(void* const* d_in, const int* in_sizes, int n_in,
                              void* d_out, int out_size, void* d_ws, size_t ws_size,
                              hipStream_t stream)
{
    const float* xyz1  = (const float*)d_in[0];
    const float* xyz2  = (const float*)d_in[1];
    const float* flow1 = (const float*)d_in[2];
    float* out = (float*)d_out;
    const int B = in_sizes[0] / (3 * N1V);

    float2* ws = (float2*)d_ws;   // B * NOCT * N2V * 3 * 8 B = 6.3 MB @ B=2

    dim3 grid(N2V / QPB, NOCT, B);    // (8, 16, B) = 256 blocks, 1/CU
    knn_part<<<grid, BLOCK, 0, stream>>>(xyz1, xyz2, flow1, ws);

    knn_merge<<<(B * N2V) / 64, 64, 0, stream>>>(xyz2, flow1, ws, out);
}

// Round 9
// 31.508 us; speedup vs baseline: 1.2245x; 1.0930x over previous
//
#include <hip/hip_runtime.h>
#include <math.h>

#define N1V    8192
#define N2V    8192
#define NCHUNK 4                  // chunks; wave w scans chunk w
#define CHUNK  (N1V / NCHUNK)     // 2048 points
#define CTILES (CHUNK / 16)       // 128 MFMA tiles per wave
#define QPB    32                 // queries per block (2 MFMA col-sets)
#define BLOCK  256                // 4 waves
#define FRAG_PB (N1V / 16 * 256)  // shorts per batch in frag table (131072)
#define SKEYMASK 0xFFFFFE00u      // stripe key: 14 mantissa bits, low 9 = stripe id
#define SMASK    0x1FFu
#define PKEYMASK 0xFFFFF800u      // point key: 12 mantissa bits, low 11 = chunk-local idx
#define PMASK    0x7FFu
#define FMAXV  __uint_as_float(0x7F7FFFFFu)

typedef __attribute__((ext_vector_type(8))) short short8;
typedef __attribute__((ext_vector_type(4))) float float4v;

#define INS3(t0,t1,t2,v) do { \
    t2 = __builtin_amdgcn_fmed3f(t1, t2, v); \
    t1 = __builtin_amdgcn_fmed3f(t0, t1, v); \
    t0 = fminf(t0, v); } while (0)

__device__ __forceinline__ void bsplit(float x, unsigned short& h, unsigned short& l) {
    unsigned hb = __float_as_uint(x) & 0xFFFF0000u;
    h = (unsigned short)(hb >> 16);
    float lo = x - __uint_as_float(hb);
    l = (unsigned short)(__float_as_uint(lo) >> 16);
}

// ---- prep: pre-split bf16 A-frag table + exact f32 point table ------------
__global__ __launch_bounds__(256)
void prep(const float* __restrict__ xyz1, const float* __restrict__ flow1,
          unsigned short* __restrict__ frag, float4* __restrict__ pts)
{
    const int j = blockIdx.x * 256 + threadIdx.x;
    const int b = j >> 13;            // /8192
    const int p = j & 8191;
    const float* x1 = xyz1 + b * 3 * N1V;
    const float* f1 = flow1 + b * 3 * N1V;
    float sx = x1[p]           + f1[p];
    float sy = x1[N1V + p]     + f1[N1V + p];
    float sz = x1[2*N1V + p]   + f1[2*N1V + p];
    float wv = fmaf(sx, sx, fmaf(sy, sy, sz * sz));
    pts[b * N1V + p] = make_float4(sx, sy, sz, wv);
    unsigned short xh,xl,yh,yl,zh,zl,wh,wl;
    bsplit(sx, xh, xl); bsplit(sy, yh, yl);
    bsplit(sz, zh, zl); bsplit(wv, wh, wl);
    unsigned base = (unsigned)b * FRAG_PB + (unsigned)(p >> 4) * 256u
                  + (unsigned)(p & 15) * 8u;
    *(uint4*)&frag[base] = make_uint4(
        (unsigned)xh | ((unsigned)yh << 16),
        (unsigned)zh | ((unsigned)xl << 16),
        (unsigned)yl | ((unsigned)zl << 16),
        (unsigned)xh | ((unsigned)yh << 16));
    *(uint4*)&frag[base + 128] = make_uint4(
        (unsigned)zh | ((unsigned)wh << 16),
        (unsigned)wl, 0u, 0u);
}

// K-slot schedule (A = point rows, B = query cols), d' = |s|^2 - 2 q.s :
//  k0-2: s_h * -2q_h   k3-5: s_l * -2q_h   k6-8: s_h * -2q_l
//  k9: w_h * 1   k10: w_l * 1   k11-31: B zero -> A content irrelevant
__global__ __launch_bounds__(BLOCK, 2)
void knn_fused(const unsigned short* __restrict__ frag,
               const float4* __restrict__ pts,
               const float* __restrict__ xyz2,
               const float* __restrict__ flow1,
               float* __restrict__ out)
{
    __shared__ float2 sCand[NCHUNK][QPB][3];   // 3 KB

    const int b     = blockIdx.y;
    const int qbase = blockIdx.x * QPB;
    const int t     = threadIdx.x;
    const int lane  = t & 63;
    const int w     = t >> 6;        // wave id == chunk id
    const int col   = lane & 15;
    const int g     = lane >> 4;

    const float* x2 = xyz2 + b * 3 * N2V;

    // ---- B fragments for 2 query column-sets ------------------------------
    short8 bfr[2];
    #pragma unroll
    for (int k = 0; k < 2; ++k) {
        int qi = qbase + k * 16 + col;
        float qx = x2[qi], qy = x2[N2V + qi], qz = x2[2*N2V + qi];
        unsigned short xh,xl,yh,yl,zh,zl;
        bsplit(-2.0f * qx, xh, xl);
        bsplit(-2.0f * qy, yh, yl);
        bsplit(-2.0f * qz, zh, zl);
        short8 bf = {0,0,0,0,0,0,0,0};
        if (g == 0) {
            bf[0]=(short)xh; bf[1]=(short)yh; bf[2]=(short)zh;
            bf[3]=(short)xh; bf[4]=(short)yh; bf[5]=(short)zh;
            bf[6]=(short)xl; bf[7]=(short)yl;
        } else if (g == 1) {
            bf[0]=(short)zl; bf[1]=(short)0x3F80; bf[2]=(short)0x3F80;  // 1.0
        }
        bfr[k] = bf;
    }
    // exact query this lane refines (k = g>>1)
    const int kk  = g >> 1;
    const int qir = qbase + kk * 16 + col;
    const float qxr = x2[qir], qyr = x2[N2V + qir], qzr = x2[2*N2V + qir];

    // ---- stream A-frags of chunk w from L2; stripe tournament -------------
    const unsigned short* fp = frag + (size_t)b * FRAG_PB
                             + (size_t)w * CTILES * 256
                             + (unsigned)(((g & 1) * 128) + col * 8);
    float c0[2] = {FMAXV, FMAXV}, c1[2] = {FMAXV, FMAXV}, c2[2] = {FMAXV, FMAXV};
    const float4v zc = {0.0f, 0.0f, 0.0f, 0.0f};
    #pragma unroll 8
    for (int tl = 0; tl < CTILES; ++tl) {
        short8 a = *(const short8*)(fp + tl * 256);
        float4v p0 = __builtin_amdgcn_mfma_f32_16x16x32_bf16(a, bfr[0], zc, 0, 0, 0);
        float4v p1 = __builtin_amdgcn_mfma_f32_16x16x32_bf16(a, bfr[1], zc, 0, 0, 0);
        unsigned sid = (unsigned)(tl << 2) | (unsigned)g;
        float m0 = fminf(fminf(fminf(p0[0], p0[1]), p0[2]), p0[3]);
        float m1 = fminf(fminf(fminf(p1[0], p1[1]), p1[2]), p1[3]);
        float k0 = __uint_as_float((__float_as_uint(m0) & SKEYMASK) | sid);
        float k1 = __uint_as_float((__float_as_uint(m1) & SKEYMASK) | sid);
        INS3(c0[0], c1[0], c2[0], k0);
        INS3(c0[1], c1[1], c2[1], k1);
    }

    // ---- butterfly merge of stripe keys across the 4 lane groups ----------
    #pragma unroll
    for (int k = 0; k < 2; ++k) {
        #pragma unroll
        for (int d = 16; d <= 32; d <<= 1) {
            float r0 = __shfl_xor(c0[k], d, 64);
            float r1 = __shfl_xor(c1[k], d, 64);
            float r2 = __shfl_xor(c2[k], d, 64);
            INS3(c0[k], c1[k], c2[k], r0);
            INS3(c0[k], c1[k], c2[k], r1);
            INS3(c0[k], c1[k], c2[k], r2);
        }
    }

    // ---- refine qset kk: 3 stripes x 4 points, exact f32 d2 ---------------
    float s0 = kk ? c0[1] : c0[0];
    float s1 = kk ? c1[1] : c1[0];
    float s2 = kk ? c2[1] : c2[0];
    const float4* cpts = pts + b * N1V + w * CHUNK;

    float e0 = FMAXV, e1 = FMAXV, e2 = FMAXV;
    #pragma unroll
    for (int m = 0; m < 3; ++m) {
        float km = (m == 0) ? s0 : (m == 1) ? s1 : s2;
        unsigned sid = __float_as_uint(km) & SMASK;
        int pb = (int)((sid >> 2) * 16 + (sid & 3) * 4);
        #pragma unroll
        for (int p = 0; p < 4; ++p) {
            int lidx = pb + p;
            float4 P = cpts[lidx];
            float dx = P.x - qxr, dy = P.y - qyr, dz = P.z - qzr;
            float d  = fmaf(dx, dx, fmaf(dy, dy, dz * dz));
            float pk = __uint_as_float((__float_as_uint(d) & PKEYMASK)
                                       | (unsigned)lidx);
            INS3(e0, e1, e2, pk);
        }
    }

    // ---- stash this chunk's triples (lanes g=0,2 own distinct queries) ----
    if (!(g & 1)) {
        const int q = kk * 16 + col;
        sCand[w][q][0] = make_float2(__uint_as_float(__float_as_uint(e0) & PKEYMASK),
                                     __int_as_float(w * CHUNK + (int)(__float_as_uint(e0) & PMASK)));
        sCand[w][q][1] = make_float2(__uint_as_float(__float_as_uint(e1) & PKEYMASK),
                                     __int_as_float(w * CHUNK + (int)(__float_as_uint(e1) & PMASK)));
        sCand[w][q][2] = make_float2(__uint_as_float(__float_as_uint(e2) & PKEYMASK),
                                     __int_as_float(w * CHUNK + (int)(__float_as_uint(e2) & PMASK)));
    }
    __syncthreads();

    // ---- final: merge 4 chunks, weights, flow gather, output --------------
    if (t < QPB) {
        float b0 = FMAXV, b1 = FMAXV, b2 = FMAXV;
        int   j0 = 0, j1 = 0, j2 = 0;
        #pragma unroll
        for (int oc = 0; oc < NCHUNK; ++oc) {
            #pragma unroll
            for (int m = 0; m < 3; ++m) {
                float2 cd = sCand[oc][t][m];
                float d = cd.x;
                int   j = __float_as_int(cd.y);
                if (d < b2) {
                    if (d < b1) {
                        b2 = b1; j2 = j1;
                        if (d < b0) { b1 = b0; j1 = j0; b0 = d; j0 = j; }
                        else        { b1 = d;  j1 = j; }
                    } else { b2 = d; j2 = j; }
                }
            }
        }
        float d0 = fmaxf(sqrtf(fmaxf(b0, 0.0f)), 1e-10f);
        float d1 = fmaxf(sqrtf(fmaxf(b1, 0.0f)), 1e-10f);
        float d2 = fmaxf(sqrtf(fmaxf(b2, 0.0f)), 1e-10f);
        float i0 = 1.0f / d0, i1 = 1.0f / d1, i2 = 1.0f / d2;
        float wsum = i0 + i1 + i2;
        float w0 = i0 / wsum, w1 = i1 / wsum, w2 = i2 / wsum;

        const float* f1 = flow1 + b * 3 * N1V;
        const int qi = qbase + t;
        float fxo = w0 * f1[j0]         + w1 * f1[j1]         + w2 * f1[j2];
        float fyo = w0 * f1[N1V + j0]   + w1 * f1[N1V + j1]   + w2 * f1[N1V + j2];
        float fzo = w0 * f1[2*N1V + j0] + w1 * f1[2*N1V + j1] + w2 * f1[2*N1V + j2];

        float* ob = out + b * 3 * N2V;
        ob[qi]         = x2[qi]         - fxo;
        ob[N2V + qi]   = x2[N2V + qi]   - fyo;
        ob[2*N2V + qi] = x2[2*N2V + qi] - fzo;
    }
}

extern "C" void kernel_launch(void* const* d_in, const int* in_sizes, int n_in,
                              void* d_out, int out_size, void* d_ws, size_t ws_size,
                              hipStream_t stream)
{
    const float* xyz1  = (const float*)d_in[0];
    const float* xyz2  = (const float*)d_in[1];
    const float* flow1 = (const float*)d_in[2];
    float* out = (float*)d_out;
    const int B = in_sizes[0] / (3 * N1V);

    unsigned short* frag = (unsigned short*)d_ws;                 // B*256 KB
    float4* pts = (float4*)((char*)d_ws + (size_t)B * FRAG_PB * 2); // B*128 KB

    prep<<<(B * N1V) / 256, 256, 0, stream>>>(xyz1, flow1, frag, pts);

    dim3 grid(N2V / QPB, B);    // (256, B) = 512 blocks, 2 blocks/CU
    knn_fused<<<grid, BLOCK, 0, stream>>>(frag, pts, xyz2, flow1, out);
}